// Round 6
// baseline (955.227 us; speedup 1.0000x reference)
//
#include <hip/hip_runtime.h>
#include <math.h>

#define NLV 16
#define NFINE 10          // levels 6..15 via feat buffer
#define NCOARSE 6         // levels 0..5 inline in mlp
#define TBL_SIZE (1u << 19)
#define TBL_MASK (TBL_SIZE - 1u)
#define NBINS 32768

// workspace float offsets
#define W1_OFF 0      // [64][35] row-major, weight-normed
#define B1_OFF 2240   // [64]
#define W2_OFF 2304   // [64]
#define B2_OFF 2368   // [1]
#define WREG   2432   // floats reserved (9728 B, 16B-aligned)

typedef float f32x4 __attribute__((ext_vector_type(4)));

struct LP {
    float scale[NLV];
    unsigned int res[NLV];
};

__device__ __forceinline__ unsigned int pack_bf16(float a, float b) {
    unsigned int ua = __float_as_uint(a);
    ua += 0x7fffu + ((ua >> 16) & 1u);           // RNE
    unsigned int ub = __float_as_uint(b);
    ub += 0x7fffu + ((ub >> 16) & 1u);
    return (ua >> 16) | (ub & 0xffff0000u);
}

// merged x-pair trilinear gather for one level (dense or hashed)
__device__ __forceinline__ void gather_level(
    const unsigned int* __restrict__ tl, bool dense, unsigned int r, float scale,
    float px, float py, float pz, float& f0, float& f1) {
    float fx = fmaf(px, scale, 0.5f);
    float fy = fmaf(py, scale, 0.5f);
    float fz = fmaf(pz, scale, 0.5f);
    float bx = floorf(fx), by = floorf(fy), bz = floorf(fz);
    float wx = fx - bx, wy = fy - by, wz = fz - bz;
    unsigned int ix = (unsigned int)bx;
    unsigned int iy = (unsigned int)by;
    unsigned int iz = (unsigned int)bz;
    f0 = 0.f; f1 = 0.f;
    float omwx = 1.f - wx;
#pragma unroll
    for (int cyz = 0; cyz < 4; ++cyz) {
        unsigned int qy = cyz >> 1, qz = cyz & 1;
        unsigned int cy = iy + qy, cz = iz + qz;
        unsigned int i0, i1;
        if (dense) {
            i0 = ix + cy * r + cz * r * r;
            i1 = i0 + 1;
        } else {
            unsigned int ryz = (cy * 2654435761u) ^ (cz * 805459861u);
            i0 = (ix ^ ryz) & TBL_MASK;
            i1 = ((ix + 1u) ^ ryz) & TBL_MASK;
        }
        unsigned int sel = i0 & 1u;
        uint2 e = *(const uint2*)(tl + (i0 & ~1u));
        unsigned int lo_bits = sel ? e.y : e.x;
        unsigned int hi_bits = sel ? e.x : e.y;
        if (i1 != (i0 ^ 1u)) hi_bits = tl[i1];   // predicated: only unmerged lanes issue

        float wrow = (qy ? wy : 1.f - wy) * (qz ? wz : 1.f - wz);
        float wlo = wrow * omwx, whi = wrow * wx;
        f0 = fmaf(wlo, __uint_as_float(lo_bits << 16), f0);
        f1 = fmaf(wlo, __uint_as_float(lo_bits & 0xffff0000u), f1);
        f0 = fmaf(whi, __uint_as_float(hi_bits << 16), f0);
        f1 = fmaf(whi, __uint_as_float(hi_bits & 0xffff0000u), f1);
    }
}

__global__ void prep_kernel(const float* __restrict__ v1, const float* __restrict__ g1,
                            const float* __restrict__ b1, const float* __restrict__ v2,
                            const float* __restrict__ g2, const float* __restrict__ b2,
                            float* __restrict__ w) {
    int j = threadIdx.x & 63;
    float s = 0.f;
#pragma unroll
    for (int k = 0; k < 35; ++k) { float x = v1[j * 35 + k]; s += x * x; }
    float sc = g1[j] / sqrtf(s);
#pragma unroll
    for (int k = 0; k < 35; ++k) w[W1_OFF + j * 35 + k] = v1[j * 35 + k] * sc;
    w[B1_OFF + j] = b1[j];
    float s2 = 0.f;
#pragma unroll
    for (int i2 = 0; i2 < 64; ++i2) { float x = v2[i2]; s2 += x * x; }
    w[W2_OFF + j] = v2[j] * (g2[0] / sqrtf(s2));
    if (j == 0) w[B2_OFF] = b2[0];
}

// f32x2 table -> packed bf16x2 (one u32 per entry)
__global__ __launch_bounds__(256) void convert_kernel(const float* __restrict__ table,
                                                      unsigned int* __restrict__ tbl4,
                                                      int total_pairs) {
    int t = blockIdx.x * 256 + threadIdx.x;
    if (t >= total_pairs) return;
    const float4 v = *(const float4*)(table + (size_t)t * 4);
    uint2 o;
    o.x = pack_bf16(v.x, v.y);
    o.y = pack_bf16(v.z, v.w);
    *(uint2*)(tbl4 + (size_t)t * 2) = o;
}

__device__ __forceinline__ unsigned int bin_key(float px, float py, float pz) {
    unsigned int ix = (unsigned int)floorf(fmaf(px, 31.f, 0.5f));
    unsigned int iy = (unsigned int)floorf(fmaf(py, 31.f, 0.5f));
    unsigned int iz = (unsigned int)floorf(fmaf(pz, 31.f, 0.5f));
    ix = min(ix, 31u); iy = min(iy, 31u); iz = min(iz, 31u);
    return ix | (iy << 5) | (iz << 10);
}

__global__ __launch_bounds__(256) void zero_hist(unsigned int* __restrict__ hist) {
    int t = blockIdx.x * 256 + threadIdx.x;
    if (t < NBINS) hist[t] = 0;
}

__global__ __launch_bounds__(256) void count_kernel(const float* __restrict__ points,
                                                    unsigned int* __restrict__ hist, int n) {
    int i = blockIdx.x * 256 + threadIdx.x;
    if (i >= n) return;
    unsigned int k = bin_key(points[3 * i], points[3 * i + 1], points[3 * i + 2]);
    atomicAdd(&hist[k], 1u);
}

// single-block exclusive scan of 32768 bins
__global__ __launch_bounds__(1024) void scan_kernel(unsigned int* __restrict__ hist) {
    __shared__ unsigned int part[1024];
    int tid = threadIdx.x;
    int base = tid * 32;
    unsigned int s = 0;
#pragma unroll
    for (int k = 0; k < 32; ++k) s += hist[base + k];
    part[tid] = s;
    __syncthreads();
    for (int d = 1; d < 1024; d <<= 1) {
        unsigned int v = (tid >= d) ? part[tid - d] : 0u;
        __syncthreads();
        part[tid] += v;
        __syncthreads();
    }
    unsigned int run = part[tid] - s;
#pragma unroll
    for (int k = 0; k < 32; ++k) {
        unsigned int t = hist[base + k];
        hist[base + k] = run;
        run += t;
    }
}

__global__ __launch_bounds__(256) void scatter_kernel(const float* __restrict__ points,
                                                      unsigned int* __restrict__ hist,
                                                      float4* __restrict__ sorted, int n) {
    int i = blockIdx.x * 256 + threadIdx.x;
    if (i >= n) return;
    float px = points[3 * i], py = points[3 * i + 1], pz = points[3 * i + 2];
    unsigned int k = bin_key(px, py, pz);
    unsigned int pos = atomicAdd(&hist[k], 1u);
    sorted[pos] = make_float4(px, py, pz, __uint_as_float((unsigned int)i));
}

// fine levels 6..15 only; one level per bpl-block slice; nt hints keep slab L2-resident
__global__ __launch_bounds__(256) void hashS_kernel(
    const float4* __restrict__ sorted, const unsigned int* __restrict__ tbl4,
    unsigned int* __restrict__ feat, LP lp, int n, int bpl) {
    int bid = blockIdx.x;
    int lv = bid / bpl;                 // 0..9
    int level = lv + NCOARSE;
    int i = (bid - lv * bpl) * 256 + threadIdx.x;
    if (i >= n) return;

    f32x4 pv = __builtin_nontemporal_load((const f32x4*)sorted + i);
    const unsigned int* tl = tbl4 + (size_t)level * TBL_SIZE;
    float f0, f1;
    gather_level(tl, false, 0u, lp.scale[level], pv.x, pv.y, pv.z, f0, f1);
    __builtin_nontemporal_store(pack_bf16(f0, f1), &feat[(size_t)lv * n + i]);
}

// coarse levels inline (line-shared gathers) + fine feats + MLP
__global__ __launch_bounds__(256) void mlpS_kernel(
    const float4* __restrict__ sorted, const unsigned int* __restrict__ tbl4,
    const unsigned int* __restrict__ feat, const float* __restrict__ w,
    float* __restrict__ out, LP lp, int n) {
    int i = blockIdx.x * 256 + threadIdx.x;
    if (i >= n) return;

    f32x4 pv = __builtin_nontemporal_load((const f32x4*)sorted + i);
    float f[35];
    f[0] = pv.x * 2.f - 1.f;
    f[1] = pv.y * 2.f - 1.f;
    f[2] = pv.z * 2.f - 1.f;
#pragma unroll
    for (int l = 0; l < NCOARSE; ++l) {
        float f0, f1;
        const unsigned int* tl = tbl4 + (size_t)l * TBL_SIZE;
        gather_level(tl, l < 4, lp.res[l], lp.scale[l], pv.x, pv.y, pv.z, f0, f1);
        f[3 + 2 * l] = f0;
        f[4 + 2 * l] = f1;
    }
#pragma unroll
    for (int l = NCOARSE; l < NLV; ++l) {
        unsigned int u = __builtin_nontemporal_load(&feat[(size_t)(l - NCOARSE) * n + i]);
        f[3 + 2 * l] = __uint_as_float(u << 16);
        f[4 + 2 * l] = __uint_as_float(u & 0xffff0000u);
    }

    float acc = w[B2_OFF];
#pragma unroll 4
    for (int j = 0; j < 64; ++j) {
        float hj = w[B1_OFF + j];
#pragma unroll
        for (int k = 0; k < 35; ++k) hj = fmaf(w[W1_OFF + j * 35 + k], f[k], hj);
        float t = 100.f * hj;
        float e = __expf(-fabsf(t));
        float sp = fmaxf(t, 0.f) + __logf(1.f + e);
        acc = fmaf(w[W2_OFF + j], sp * 0.01f, acc);
    }
    out[__float_as_uint(pv.w)] = acc;
}

// fully fused fallback (tiny ws)
__global__ __launch_bounds__(256) void sdf_fused_kernel(
    const float* __restrict__ points, const float* __restrict__ table,
    const float* __restrict__ w, float* __restrict__ out, LP lp, int n) {
    int i = blockIdx.x * 256 + threadIdx.x;
    if (i >= n) return;
    float px = points[3 * i], py = points[3 * i + 1], pz = points[3 * i + 2];
    float f[35];
    f[0] = px * 2.f - 1.f; f[1] = py * 2.f - 1.f; f[2] = pz * 2.f - 1.f;
#pragma unroll
    for (int l = 0; l < NLV; ++l) {
        float scale = lp.scale[l];
        float fx = fmaf(px, scale, 0.5f), fy = fmaf(py, scale, 0.5f), fz = fmaf(pz, scale, 0.5f);
        float bx = floorf(fx), by = floorf(fy), bz = floorf(fz);
        float wx = fx - bx, wy = fy - by, wz = fz - bz;
        unsigned int ix = (unsigned int)bx, iy = (unsigned int)by, iz = (unsigned int)bz;
        const float* tl = table + (size_t)l * (TBL_SIZE * 2);
        float f0 = 0.f, f1 = 0.f;
#pragma unroll
        for (int c = 0; c < 8; ++c) {
            unsigned int qx = (c >> 2) & 1, qy = (c >> 1) & 1, qz = c & 1;
            unsigned int cx = ix + qx, cy = iy + qy, cz = iz + qz;
            unsigned int idx;
            if (l < 4) { unsigned int rr = lp.res[l]; idx = cx + cy * rr + cz * rr * rr; }
            else { idx = (cx * 1u) ^ (cy * 2654435761u) ^ (cz * 805459861u); idx &= TBL_MASK; }
            float cw = (qx ? wx : 1.f - wx) * (qy ? wy : 1.f - wy) * (qz ? wz : 1.f - wz);
            float2 g2v = *(const float2*)(tl + (size_t)idx * 2);
            f0 = fmaf(cw, g2v.x, f0); f1 = fmaf(cw, g2v.y, f1);
        }
        f[3 + 2 * l] = f0; f[4 + 2 * l] = f1;
    }
    float acc = w[B2_OFF];
#pragma unroll 4
    for (int j = 0; j < 64; ++j) {
        float hj = w[B1_OFF + j];
#pragma unroll
        for (int k = 0; k < 35; ++k) hj = fmaf(w[W1_OFF + j * 35 + k], f[k], hj);
        float t = 100.f * hj;
        float e = __expf(-fabsf(t));
        float sp = fmaxf(t, 0.f) + __logf(1.f + e);
        acc = fmaf(w[W2_OFF + j], sp * 0.01f, acc);
    }
    out[i] = acc;
}

extern "C" void kernel_launch(void* const* d_in, const int* in_sizes, int n_in,
                              void* d_out, int out_size, void* d_ws, size_t ws_size,
                              hipStream_t stream) {
    const float* points = (const float*)d_in[0];
    const float* table  = (const float*)d_in[1];
    const float* v1 = (const float*)d_in[2];
    const float* g1 = (const float*)d_in[3];
    const float* b1 = (const float*)d_in[4];
    const float* v2 = (const float*)d_in[5];
    const float* g2 = (const float*)d_in[6];
    const float* b2 = (const float*)d_in[7];
    float* out = (float*)d_out;
    float* w = (float*)d_ws;

    int n = in_sizes[0] / 3;

    LP lp;
    for (int l = 0; l < NLV; ++l) {
        double s = 32.0 * pow(1.3195079107728942, (double)l) - 1.0;
        lp.scale[l] = (float)s;
        lp.res[l] = (unsigned int)(ceil(s)) + 1u;
    }

    prep_kernel<<<1, 64, 0, stream>>>(v1, g1, b1, v2, g2, b2, w);

    // ws layout (u32/float slots): weights | feat[10*n] | tbl4[16*TBL] | sorted f4[n] | hist
    size_t off_feat = WREG;
    size_t off_tbl4 = off_feat + (size_t)NFINE * n;
    size_t off_sort = off_tbl4 + (size_t)NLV * TBL_SIZE;
    size_t off_hist = off_sort + (size_t)4 * n;
    size_t need = (off_hist + NBINS) * 4;

    int blocks = (n + 255) / 256;
    if (ws_size >= need) {
        unsigned int* feat = (unsigned int*)d_ws + off_feat;
        unsigned int* tbl4 = (unsigned int*)d_ws + off_tbl4;
        float4* sorted = (float4*)((float*)d_ws + off_sort);
        unsigned int* hist = (unsigned int*)d_ws + off_hist;

        int total_pairs = NLV * TBL_SIZE / 2;
        convert_kernel<<<(total_pairs + 255) / 256, 256, 0, stream>>>(table, tbl4, total_pairs);
        zero_hist<<<(NBINS + 255) / 256, 256, 0, stream>>>(hist);
        count_kernel<<<blocks, 256, 0, stream>>>(points, hist, n);
        scan_kernel<<<1, 1024, 0, stream>>>(hist);
        scatter_kernel<<<blocks, 256, 0, stream>>>(points, hist, sorted, n);
        hashS_kernel<<<NFINE * blocks, 256, 0, stream>>>(sorted, tbl4, feat, lp, n, blocks);
        mlpS_kernel<<<blocks, 256, 0, stream>>>(sorted, tbl4, feat, w, out, lp, n);
    } else {
        sdf_fused_kernel<<<blocks, 256, 0, stream>>>(points, table, w, out, lp, n);
    }
}

// Round 8
// 903.996 us; speedup vs baseline: 1.0567x; 1.0567x over previous
//
#include <hip/hip_runtime.h>
#include <math.h>

#define NLV 16
#define NFINE 10          // levels 6..15 via feat buffer
#define NCOARSE 6         // levels 0..5 inline in mlp
#define TBL_SIZE (1u << 19)
#define TBL_MASK (TBL_SIZE - 1u)
#define NBINS 32768

// workspace float offsets
#define W1_OFF 0      // [64][35] row-major, weight-normed
#define B1_OFF 2240   // [64]
#define W2_OFF 2304   // [64]
#define B2_OFF 2368   // [1]
#define WREG   2432   // floats reserved (9728 B, 16B-aligned)

typedef float f32x4 __attribute__((ext_vector_type(4)));

struct LP {
    float scale[NLV];
    unsigned int res[NLV];
};

__device__ __forceinline__ unsigned int pack_bf16(float a, float b) {
    unsigned int ua = __float_as_uint(a);
    ua += 0x7fffu + ((ua >> 16) & 1u);           // RNE
    unsigned int ub = __float_as_uint(b);
    ub += 0x7fffu + ((ub >> 16) & 1u);
    return (ua >> 16) | (ub & 0xffff0000u);
}

// merged x-pair trilinear gather for one level (dense or hashed)
__device__ __forceinline__ void gather_level(
    const unsigned int* __restrict__ tl, bool dense, unsigned int r, float scale,
    float px, float py, float pz, float& f0, float& f1) {
    float fx = fmaf(px, scale, 0.5f);
    float fy = fmaf(py, scale, 0.5f);
    float fz = fmaf(pz, scale, 0.5f);
    float bx = floorf(fx), by = floorf(fy), bz = floorf(fz);
    float wx = fx - bx, wy = fy - by, wz = fz - bz;
    unsigned int ix = (unsigned int)bx;
    unsigned int iy = (unsigned int)by;
    unsigned int iz = (unsigned int)bz;
    f0 = 0.f; f1 = 0.f;
    float omwx = 1.f - wx;
#pragma unroll
    for (int cyz = 0; cyz < 4; ++cyz) {
        unsigned int qy = cyz >> 1, qz = cyz & 1;
        unsigned int cy = iy + qy, cz = iz + qz;
        unsigned int i0, i1;
        if (dense) {
            i0 = ix + cy * r + cz * r * r;
            i1 = i0 + 1;
        } else {
            unsigned int ryz = (cy * 2654435761u) ^ (cz * 805459861u);
            i0 = (ix ^ ryz) & TBL_MASK;
            i1 = ((ix + 1u) ^ ryz) & TBL_MASK;
        }
        unsigned int sel = i0 & 1u;
        uint2 e = *(const uint2*)(tl + (i0 & ~1u));
        unsigned int lo_bits = sel ? e.y : e.x;
        unsigned int hi_bits = sel ? e.x : e.y;
        if (i1 != (i0 ^ 1u)) hi_bits = tl[i1];   // predicated: only unmerged lanes issue

        float wrow = (qy ? wy : 1.f - wy) * (qz ? wz : 1.f - wz);
        float wlo = wrow * omwx, whi = wrow * wx;
        f0 = fmaf(wlo, __uint_as_float(lo_bits << 16), f0);
        f1 = fmaf(wlo, __uint_as_float(lo_bits & 0xffff0000u), f1);
        f0 = fmaf(whi, __uint_as_float(hi_bits << 16), f0);
        f1 = fmaf(whi, __uint_as_float(hi_bits & 0xffff0000u), f1);
    }
}

// block 0: weight-norm prep; blocks 1..: zero hist (separate dispatch -> ordered before count)
__global__ __launch_bounds__(256) void prep_kernel(
    const float* __restrict__ v1, const float* __restrict__ g1,
    const float* __restrict__ b1, const float* __restrict__ v2,
    const float* __restrict__ g2, const float* __restrict__ b2,
    float* __restrict__ w, unsigned int* __restrict__ hist) {
    int bid = blockIdx.x;
    if (bid > 0) {
        int t = (bid - 1) * 256 + threadIdx.x;
        if (t < NBINS) hist[t] = 0;
        return;
    }
    if (threadIdx.x >= 64) return;
    int j = threadIdx.x;
    float s = 0.f;
#pragma unroll
    for (int k = 0; k < 35; ++k) { float x = v1[j * 35 + k]; s += x * x; }
    float sc = g1[j] / sqrtf(s);
#pragma unroll
    for (int k = 0; k < 35; ++k) w[W1_OFF + j * 35 + k] = v1[j * 35 + k] * sc;
    w[B1_OFF + j] = b1[j];
    float s2 = 0.f;
#pragma unroll
    for (int i2 = 0; i2 < 64; ++i2) { float x = v2[i2]; s2 += x * x; }
    w[W2_OFF + j] = v2[j] * (g2[0] / sqrtf(s2));
    if (j == 0) w[B2_OFF] = b2[0];
}

__device__ __forceinline__ unsigned int bin_key(float px, float py, float pz) {
    unsigned int ix = (unsigned int)floorf(fmaf(px, 31.f, 0.5f));
    unsigned int iy = (unsigned int)floorf(fmaf(py, 31.f, 0.5f));
    unsigned int iz = (unsigned int)floorf(fmaf(pz, 31.f, 0.5f));
    ix = min(ix, 31u); iy = min(iy, 31u); iz = min(iz, 31u);
    return ix | (iy << 5) | (iz << 10);
}

// fused: table convert | bin count  (disjoint outputs; no intra-dispatch ordering needed)
__global__ __launch_bounds__(256) void aux_kernel(
    const float* __restrict__ table, unsigned int* __restrict__ tbl4,
    unsigned int* __restrict__ hist, const float* __restrict__ points,
    int n, int cvt_blocks) {
    int bid = blockIdx.x;
    if (bid < cvt_blocks) {
        int t = bid * 256 + threadIdx.x;
        int total_pairs = NLV * TBL_SIZE / 2;
        if (t >= total_pairs) return;
        const float4 v = *(const float4*)(table + (size_t)t * 4);
        uint2 o;
        o.x = pack_bf16(v.x, v.y);
        o.y = pack_bf16(v.z, v.w);
        *(uint2*)(tbl4 + (size_t)t * 2) = o;
    } else {
        int i = (bid - cvt_blocks) * 256 + threadIdx.x;
        if (i >= n) return;
        unsigned int k = bin_key(points[3 * i], points[3 * i + 1], points[3 * i + 2]);
        atomicAdd(&hist[k], 1u);
    }
}

// single-block exclusive scan of 32768 bins
__global__ __launch_bounds__(1024) void scan_kernel(unsigned int* __restrict__ hist) {
    __shared__ unsigned int part[1024];
    int tid = threadIdx.x;
    int base = tid * 32;
    unsigned int s = 0;
#pragma unroll
    for (int k = 0; k < 32; ++k) s += hist[base + k];
    part[tid] = s;
    __syncthreads();
    for (int d = 1; d < 1024; d <<= 1) {
        unsigned int v = (tid >= d) ? part[tid - d] : 0u;
        __syncthreads();
        part[tid] += v;
        __syncthreads();
    }
    unsigned int run = part[tid] - s;
#pragma unroll
    for (int k = 0; k < 32; ++k) {
        unsigned int t = hist[base + k];
        hist[base + k] = run;
        run += t;
    }
}

__global__ __launch_bounds__(256) void scatter_kernel(const float* __restrict__ points,
                                                      unsigned int* __restrict__ hist,
                                                      float4* __restrict__ sorted, int n) {
    int i = blockIdx.x * 256 + threadIdx.x;
    if (i >= n) return;
    float px = points[3 * i], py = points[3 * i + 1], pz = points[3 * i + 2];
    unsigned int k = bin_key(px, py, pz);
    unsigned int pos = atomicAdd(&hist[k], 1u);
    sorted[pos] = make_float4(px, py, pz, __uint_as_float((unsigned int)i));
}

// fine levels 6..15; one level per bpl-block slice; sorted reads via L2/L3 (reused 10x)
__global__ __launch_bounds__(256) void hashS_kernel(
    const float4* __restrict__ sorted, const unsigned int* __restrict__ tbl4,
    unsigned int* __restrict__ feat, LP lp, int n, int bpl) {
    int bid = blockIdx.x;
    int lv = bid / bpl;                 // 0..9
    int level = lv + NCOARSE;
    int i = (bid - lv * bpl) * 256 + threadIdx.x;
    if (i >= n) return;

    float4 p = sorted[i];
    const unsigned int* tl = tbl4 + (size_t)level * TBL_SIZE;
    float f0, f1;
    gather_level(tl, false, 0u, lp.scale[level], p.x, p.y, p.z, f0, f1);
    __builtin_nontemporal_store(pack_bf16(f0, f1), &feat[(size_t)lv * n + i]);
}

// coarse levels inline (line-shared gathers) + fine feats + MLP
__global__ __launch_bounds__(256) void mlpS_kernel(
    const float4* __restrict__ sorted, const unsigned int* __restrict__ tbl4,
    const unsigned int* __restrict__ feat, const float* __restrict__ w,
    float* __restrict__ out, LP lp, int n) {
    int i = blockIdx.x * 256 + threadIdx.x;
    if (i >= n) return;

    float4 p = sorted[i];
    float f[35];
    f[0] = p.x * 2.f - 1.f;
    f[1] = p.y * 2.f - 1.f;
    f[2] = p.z * 2.f - 1.f;
#pragma unroll
    for (int l = 0; l < NCOARSE; ++l) {
        float f0, f1;
        const unsigned int* tl = tbl4 + (size_t)l * TBL_SIZE;
        gather_level(tl, l < 4, lp.res[l], lp.scale[l], p.x, p.y, p.z, f0, f1);
        f[3 + 2 * l] = f0;
        f[4 + 2 * l] = f1;
    }
#pragma unroll
    for (int l = NCOARSE; l < NLV; ++l) {
        unsigned int u = __builtin_nontemporal_load(&feat[(size_t)(l - NCOARSE) * n + i]);
        f[3 + 2 * l] = __uint_as_float(u << 16);
        f[4 + 2 * l] = __uint_as_float(u & 0xffff0000u);
    }

    float acc = w[B2_OFF];
#pragma unroll 4
    for (int j = 0; j < 64; ++j) {
        float hj = w[B1_OFF + j];
#pragma unroll
        for (int k = 0; k < 35; ++k) hj = fmaf(w[W1_OFF + j * 35 + k], f[k], hj);
        float t = 100.f * hj;
        float e = __expf(-fabsf(t));
        float sp = fmaxf(t, 0.f) + __logf(1.f + e);
        acc = fmaf(w[W2_OFF + j], sp * 0.01f, acc);
    }
    out[__float_as_uint(p.w)] = acc;
}

// fully fused fallback (tiny ws)
__global__ __launch_bounds__(256) void sdf_fused_kernel(
    const float* __restrict__ points, const float* __restrict__ table,
    const float* __restrict__ w, float* __restrict__ out, LP lp, int n) {
    int i = blockIdx.x * 256 + threadIdx.x;
    if (i >= n) return;
    float px = points[3 * i], py = points[3 * i + 1], pz = points[3 * i + 2];
    float f[35];
    f[0] = px * 2.f - 1.f; f[1] = py * 2.f - 1.f; f[2] = pz * 2.f - 1.f;
#pragma unroll
    for (int l = 0; l < NLV; ++l) {
        float scale = lp.scale[l];
        float fx = fmaf(px, scale, 0.5f), fy = fmaf(py, scale, 0.5f), fz = fmaf(pz, scale, 0.5f);
        float bx = floorf(fx), by = floorf(fy), bz = floorf(fz);
        float wx = fx - bx, wy = fy - by, wz = fz - bz;
        unsigned int ix = (unsigned int)bx, iy = (unsigned int)by, iz = (unsigned int)bz;
        const float* tl = table + (size_t)l * (TBL_SIZE * 2);
        float f0 = 0.f, f1 = 0.f;
#pragma unroll
        for (int c = 0; c < 8; ++c) {
            unsigned int qx = (c >> 2) & 1, qy = (c >> 1) & 1, qz = c & 1;
            unsigned int cx = ix + qx, cy = iy + qy, cz = iz + qz;
            unsigned int idx;
            if (l < 4) { unsigned int rr = lp.res[l]; idx = cx + cy * rr + cz * rr * rr; }
            else { idx = (cx * 1u) ^ (cy * 2654435761u) ^ (cz * 805459861u); idx &= TBL_MASK; }
            float cw = (qx ? wx : 1.f - wx) * (qy ? wy : 1.f - wy) * (qz ? wz : 1.f - wz);
            float2 g2v = *(const float2*)(tl + (size_t)idx * 2);
            f0 = fmaf(cw, g2v.x, f0); f1 = fmaf(cw, g2v.y, f1);
        }
        f[3 + 2 * l] = f0; f[4 + 2 * l] = f1;
    }
    float acc = w[B2_OFF];
#pragma unroll 4
    for (int j = 0; j < 64; ++j) {
        float hj = w[B1_OFF + j];
#pragma unroll
        for (int k = 0; k < 35; ++k) hj = fmaf(w[W1_OFF + j * 35 + k], f[k], hj);
        float t = 100.f * hj;
        float e = __expf(-fabsf(t));
        float sp = fmaxf(t, 0.f) + __logf(1.f + e);
        acc = fmaf(w[W2_OFF + j], sp * 0.01f, acc);
    }
    out[i] = acc;
}

extern "C" void kernel_launch(void* const* d_in, const int* in_sizes, int n_in,
                              void* d_out, int out_size, void* d_ws, size_t ws_size,
                              hipStream_t stream) {
    const float* points = (const float*)d_in[0];
    const float* table  = (const float*)d_in[1];
    const float* v1 = (const float*)d_in[2];
    const float* g1 = (const float*)d_in[3];
    const float* b1 = (const float*)d_in[4];
    const float* v2 = (const float*)d_in[5];
    const float* g2 = (const float*)d_in[6];
    const float* b2 = (const float*)d_in[7];
    float* out = (float*)d_out;
    float* w = (float*)d_ws;

    int n = in_sizes[0] / 3;

    LP lp;
    for (int l = 0; l < NLV; ++l) {
        double s = 32.0 * pow(1.3195079107728942, (double)l) - 1.0;
        lp.scale[l] = (float)s;
        lp.res[l] = (unsigned int)(ceil(s)) + 1u;
    }

    // ws layout (u32/float slots): weights | feat[10*n] | tbl4[16*TBL] | sorted f4[n] | hist
    size_t off_feat = WREG;
    size_t off_tbl4 = off_feat + (size_t)NFINE * n;
    size_t off_sort = off_tbl4 + (size_t)NLV * TBL_SIZE;
    size_t off_hist = off_sort + (size_t)4 * n;
    size_t need = (off_hist + NBINS) * 4;

    int blocks = (n + 255) / 256;
    int hist_blocks = (NBINS + 255) / 256;
    if (ws_size >= need) {
        unsigned int* feat = (unsigned int*)d_ws + off_feat;
        unsigned int* tbl4 = (unsigned int*)d_ws + off_tbl4;
        float4* sorted = (float4*)((float*)d_ws + off_sort);
        unsigned int* hist = (unsigned int*)d_ws + off_hist;

        int total_pairs = NLV * TBL_SIZE / 2;
        int cvt_blocks = (total_pairs + 255) / 256;
        prep_kernel<<<1 + hist_blocks, 256, 0, stream>>>(v1, g1, b1, v2, g2, b2, w, hist);
        aux_kernel<<<cvt_blocks + blocks, 256, 0, stream>>>(table, tbl4, hist, points, n, cvt_blocks);
        scan_kernel<<<1, 1024, 0, stream>>>(hist);
        scatter_kernel<<<blocks, 256, 0, stream>>>(points, hist, sorted, n);
        hashS_kernel<<<NFINE * blocks, 256, 0, stream>>>(sorted, tbl4, feat, lp, n, blocks);
        mlpS_kernel<<<blocks, 256, 0, stream>>>(sorted, tbl4, feat, w, out, lp, n);
    } else {
        prep_kernel<<<1, 256, 0, stream>>>(v1, g1, b1, v2, g2, b2, w, (unsigned int*)d_ws);
        sdf_fused_kernel<<<blocks, 256, 0, stream>>>(points, table, w, out, lp, n);
    }
}